// Round 3
// baseline (623.349 us; speedup 1.0000x reference)
//
#include <hip/hip_runtime.h>

// LocSE: B=4, N=16384, DIMS=2, K1=17, CH=53, UNITS=128 (UH=64)
// Inputs: pc(4,16384,2) f32, feats(4,16384,64) f32, n_idx(4,16384,17) i32,
//         W(53,64) f32, b(64) f32
// Outputs (concat flat): out(4,16384,17,128) f32 then ggf(4,16384,1,2) f32
//
// Algebra: for output row j,
//   r[j][u] = relu(b[u] + G[u] + p_jx*(W0-SWx) + p_jy*(W1-SWy) + nr_j*SWn)
// with G[u] = sum_i (p_ix*Wx_i[u] + p_iy*Wy_i[u])  (j-independent),
//      SWx/SWy/SWn = column sums over i of the per-i W rows.
// (reference broadcasts norms[j] across i, hence single nr_j*SWn term)
//
// R3: u = lane (64 lanes = 64 units — R2's u=lane*2 read W/feats OOB, fault).
// Kept from R2: shfl broadcast (no LDS/barrier), batch = blockIdx&3 XCD<->L2
// partition, feats gathers prefetched into registers ahead of the W loop.

#define NB 16384
#define K1C 17
#define UH 64

static constexpr long long OUT_R = 4LL * NB * K1C * 128; // 142606336

__global__ __launch_bounds__(256) void locse_kernel(
    const float* __restrict__ pc,
    const float* __restrict__ feats,
    const int*   __restrict__ n_idx,
    const float* __restrict__ W,
    const float* __restrict__ bias,
    float* __restrict__ out)
{
    const int wave = threadIdx.x >> 6;
    const int lane = threadIdx.x & 63;
    const int b = blockIdx.x & 3;          // batch <-> XCD (blockIdx%8 -> XCD)
    const int g = blockIdx.x >> 2;         // point-group within batch
    const long long p = (long long)b * NB + g * 4 + wave;  // global point

    // lanes 0..16 hold the 17 neighbour ids/coords (others duplicate lane 16)
    const int li = lane < K1C ? lane : K1C - 1;
    const int id_l = n_idx[p * K1C + li];
    const float2 pp = *(const float2*)(pc + ((long long)b * NB + id_l) * 2);
    const float px_l = pp.x, py_l = pp.y;
    const float nr_l = sqrtf(fmaf(pp.x, pp.x, pp.y * pp.y));

    const int u = lane;                    // one MLP unit per lane
    const long long fb = (long long)b * NB * UH;

    // prefetch the 17 gathered feats rows (each a coalesced 256B load)
    int ids[K1C];
#pragma unroll
    for (int j = 0; j < K1C; ++j) ids[j] = __shfl(id_l, j);  // v_readlane
    float fv[K1C];
#pragma unroll
    for (int j = 0; j < K1C; ++j)
        fv[j] = feats[fb + (long long)ids[j] * UH + u];

    float w0 = W[u];        // W[0][u]
    float w1 = W[UH + u];   // W[1][u]
    const float* Wr = W + 2 * UH + u;      // rows 2.. , column u (u<64: in-bounds)

    float G = 0.f, swx = 0.f, swy = 0.f, swn = 0.f;
    float sx = 0.f, sy = 0.f, sxx = 0.f, syy = 0.f, sxy = 0.f;
#pragma unroll
    for (int i = 0; i < K1C; ++i) {
        float px = __shfl(px_l, i);
        float py = __shfl(py_l, i);
        float wx = Wr[(3 * i + 0) * UH];   // max row 52 = CH-1, in-bounds
        float wy = Wr[(3 * i + 1) * UH];
        float wn = Wr[(3 * i + 2) * UH];
        G = fmaf(px, wx, G);
        G = fmaf(py, wy, G);
        swx += wx; swy += wy; swn += wn;
        sx += px;  sy += py;
        sxx = fmaf(px, px, sxx);
        syy = fmaf(py, py, syy);
        sxy = fmaf(px, py, sxy);
    }
    const float base = bias[u] + G;
    const float c0 = w0 - swx;
    const float c1 = w1 - swy;

    float* orow = out + p * (K1C * 128);
#pragma unroll
    for (int j = 0; j < K1C; ++j) {
        float px = __shfl(px_l, j);
        float py = __shfl(py_l, j);
        float nr = __shfl(nr_l, j);
        float v = fmaxf(fmaf(px, c0, fmaf(py, c1, fmaf(nr, swn, base))), 0.f);
        orow[j * 128 + u]      = fv[j];    // n_feats half (cols 0..63)
        orow[j * 128 + UH + u] = v;        // relu-MLP half (cols 64..127)
    }

    // ggf: slope + (1 - pearson); sums are wave-uniform, lane 0 writes
    if (lane == 0) {
        const float inv = 1.0f / 17.0f;
        float mx = sx * inv, my = sy * inv;
        float cov = sxy * inv - mx * my;
        float vx = fmaxf(sxx * inv - mx * mx, 0.f);
        float vy = fmaxf(syy * inv - my * my, 0.f);
        float m = cov / (vx + 1e-8f);
        float pear = cov / (sqrtf(vx * vy) + 1e-8f);
        out[OUT_R + p * 2 + 0] = m;
        out[OUT_R + p * 2 + 1] = 1.0f - pear;
    }
}

extern "C" void kernel_launch(void* const* d_in, const int* in_sizes, int n_in,
                              void* d_out, int out_size, void* d_ws, size_t ws_size,
                              hipStream_t stream) {
    const float* pc    = (const float*)d_in[0];
    const float* feats = (const float*)d_in[1];
    const int*   n_idx = (const int*)d_in[2];
    const float* W     = (const float*)d_in[3];
    const float* bias  = (const float*)d_in[4];
    float* out = (float*)d_out;

    // 65536 points, 4 per block (one wave each), 256 threads
    locse_kernel<<<16384, 256, 0, stream>>>(pc, feats, n_idx, W, bias, out);
}